// Round 12
// baseline (664.757 us; speedup 1.0000x reference)
//
#include <hip/hip_runtime.h>

#define NN 20000
#define NE 320000
#define HD 128
#define NBLK ((NN + 255) / 256)   // 79

typedef short     s16x8 __attribute__((ext_vector_type(8)));
typedef unsigned short u16x8 __attribute__((ext_vector_type(8)));
typedef float     f32x4 __attribute__((ext_vector_type(4)));

__device__ __forceinline__ float b2f(unsigned short u) {
    union { unsigned int i; float f; } c; c.i = ((unsigned int)u) << 16; return c.f;
}
__device__ __forceinline__ unsigned short f2b(float f) {
    union { float f; unsigned int i; } c; c.f = f;
    unsigned int x = c.i + 0x7FFFu + ((c.i >> 16) & 1u);
    return (unsigned short)(x >> 16);
}

// ---------------- CSR build ----------------
__global__ void zero_cnt(int* __restrict__ cnt) {
    int i = blockIdx.x * 256 + threadIdx.x;
    if (i < NN) cnt[i] = 0;
}

__global__ void hist_kernel(const int* __restrict__ ei, int* __restrict__ cnt) {
    int e = blockIdx.x * 256 + threadIdx.x;
    if (e < NE) atomicAdd(&cnt[ei[NE + e]], 1);
}

__global__ void scan1_kernel(const int* __restrict__ cnt, int* __restrict__ rowptr,
                             int* __restrict__ bsum, int* __restrict__ cursor) {
    __shared__ int s[256];
    int t = threadIdx.x;
    int i = blockIdx.x * 256 + t;
    if (i < NN) cursor[i] = 0;
    int v = (i < NN) ? cnt[i] : 0;
    s[t] = v; __syncthreads();
    #pragma unroll
    for (int off = 1; off < 256; off <<= 1) {
        int add = (t >= off) ? s[t - off] : 0;
        __syncthreads();
        s[t] += add;
        __syncthreads();
    }
    if (i < NN) rowptr[i] = s[t] - v;
    if (t == 255) bsum[blockIdx.x] = s[t];
}

__global__ void scan2_kernel(int* __restrict__ bsum, int* __restrict__ boffs) {
    __shared__ int s[256];
    int t = threadIdx.x;
    int v = (t < NBLK) ? bsum[t] : 0;
    s[t] = v; __syncthreads();
    #pragma unroll
    for (int off = 1; off < 256; off <<= 1) {
        int add = (t >= off) ? s[t - off] : 0;
        __syncthreads();
        s[t] += add;
        __syncthreads();
    }
    if (t < NBLK) boffs[t] = s[t] - v;
}

__global__ void scan3_kernel(int* __restrict__ rowptr, const int* __restrict__ boffs) {
    int i = blockIdx.x * 256 + threadIdx.x;
    if (i < NN) rowptr[i] += boffs[blockIdx.x];
    if (i == 0) rowptr[NN] = NE;
}

__global__ void scatter_kernel(const int* __restrict__ ei, const float* __restrict__ ea,
                               const int* __restrict__ rowptr, int* __restrict__ cursor,
                               int* __restrict__ srcS, float* __restrict__ eaS) {
    int e = blockIdx.x * 256 + threadIdx.x;
    if (e >= NE) return;
    int d = ei[NE + e];
    int pos = rowptr[d] + atomicAdd(&cursor[d], 1);
    srcS[pos] = ei[e];
    *(float4*)(eaS + (long long)pos * 4) = *(const float4*)(ea + (long long)e * 4);
}

// ---------------- all weight transposes in one dispatch (grid.y = 15)
__global__ void cvt_all(const float* __restrict__ WeM, const float* __restrict__ WnM,
                        const float* __restrict__ WeC, const float* __restrict__ WnC,
                        const float* __restrict__ Wn1,
                        unsigned short* __restrict__ WTeM, unsigned short* __restrict__ WTnM,
                        unsigned short* __restrict__ WTeC, unsigned short* __restrict__ WTnC,
                        unsigned short* __restrict__ WTn1) {
    int y = blockIdx.y;
    const float* W; unsigned short* WT; int K;
    if (y < 6)       { W = WeM + (size_t)y * 132 * HD;       WT = WTeM + (size_t)y * HD * 128; K = 128; }
    else if (y < 12) { int i = y - 6;
                       W = WnM + (size_t)i * 256 * HD;       WT = WTnM + (size_t)i * HD * 256; K = 256; }
    else if (y == 12){ W = WeC;                              WT = WTeC;                        K = 896; }
    else if (y == 13){ W = WnC;                              WT = WTnC;                        K = 1024; }
    else             { W = Wn1 + 8 * HD;                     WT = WTn1;                        K = 128; }
    int tid = blockIdx.x * 256 + threadIdx.x;
    if (tid >= K * HD) return;
    int n = tid & (HD - 1), k = tid >> 7;
    WT[(size_t)n * K + k] = f2b(W[(size_t)k * HD + n]);
}

// ---------------- layer-1 dual projection
__global__ void proj8_dual(const float* __restrict__ x,
                           const float* __restrict__ We1, const float* __restrict__ Wn1,
                           const float* __restrict__ bn1,
                           unsigned short* __restrict__ P, float* __restrict__ B1) {
    int t = blockIdx.x * 256 + threadIdx.x;
    int n = t >> 7, j = t & 127;
    const float* xr = x + (long long)n * 8;
    float a = 0.f, b = bn1[j];
    #pragma unroll
    for (int k = 0; k < 8; ++k) {
        float xv = xr[k];
        a = fmaf(xv, We1[k * HD + j], a);
        b = fmaf(xv, Wn1[k * HD + j], b);
    }
    P[t]  = f2b(a);
    B1[t] = b;
}

// ---------------- fused layer kernel, BM=128, 4 waves (2x2), N=128.
// Phase A (EDGE): per-block gather-aggregate Agg[128 nodes][128] into LDS (slot-major).
// Phase B: C = [relu](A @ WTn [+ bias | + addF]); A = [seg1 (D1 cols) | AggS (128 cols)].
// Phase C (PROJ): P = C @ WTe -> Pout. (PROJ8): PL = C @ WeLf -> PLout (8 cols, VALU).
template<bool EDGE, bool ACT, bool ADDF, bool PROJ, bool PROJ8>
__global__ __launch_bounds__(256)
void mfma_fused(const unsigned short* __restrict__ seg1, long long s1, int xoff, int D1,
                const unsigned short* __restrict__ Pread,
                const int* __restrict__ srcS, const int* __restrict__ rowptr,
                const float* __restrict__ eaS,
                const float* __restrict__ eWea, const float* __restrict__ ebias,
                const unsigned short* __restrict__ WTn, const float* __restrict__ bias,
                const float* __restrict__ addF,
                unsigned short* __restrict__ OutB, long long ostride, int ooff,
                const unsigned short* __restrict__ WTe,
                unsigned short* __restrict__ Pout,
                const float* __restrict__ WeLf, float* __restrict__ PLout,
                int M, int K)
{
    __shared__ unsigned short As[4 * 128 * 8];
    __shared__ unsigned short Bs[4 * 128 * 8];
    __shared__ unsigned short CsAgg[(EDGE || PROJ || PROJ8) ? 16 * 128 * 8 : 8];
    __shared__ float sWL[PROJ8 ? 128 * 8 : 1];

    const int t    = threadIdx.x;
    const int lane = t & 63;
    const int wid  = t >> 6;
    const int wm   = wid >> 1, wn = wid & 1;
    const int ln   = lane & 15, kb = lane >> 4;
    const int bRow = blockIdx.x * 128;

    if (PROJ8) {
        for (int i = t; i < 128 * 8; i += 256) sWL[i] = WeLf[i];
    }

    // ---- phase A: edge aggregation into CsAgg (slot-major: [cg 0..15][row 0..127][8])
    if (EDGE) {
        const int cg = t & 15;
        float wea[4][8], bv8[8];
        #pragma unroll
        for (int c = 0; c < 4; ++c)
            #pragma unroll
            for (int j = 0; j < 8; ++j) wea[c][j] = eWea[c * HD + cg * 8 + j];
        #pragma unroll
        for (int j = 0; j < 8; ++j) bv8[j] = ebias[cg * 8 + j];

        for (int g = 0; g < 8; ++g) {
            int nl = g * 16 + (t >> 4);
            int n  = bRow + nl;
            float acc[8];
            #pragma unroll
            for (int j = 0; j < 8; ++j) acc[j] = 0.f;
            if (n < M) {
                int s = rowptr[n], e = rowptr[n + 1];
                int p = s;
                for (; p + 4 <= e; p += 4) {
                    int s0 = srcS[p + 0], s1 = srcS[p + 1], s2 = srcS[p + 2], s3 = srcS[p + 3];
                    u16x8 pv0 = *(const u16x8*)(Pread + (long long)s0 * HD + cg * 8);
                    u16x8 pv1 = *(const u16x8*)(Pread + (long long)s1 * HD + cg * 8);
                    u16x8 pv2 = *(const u16x8*)(Pread + (long long)s2 * HD + cg * 8);
                    u16x8 pv3 = *(const u16x8*)(Pread + (long long)s3 * HD + cg * 8);
                    float4 e0 = *(const float4*)(eaS + (long long)(p + 0) * 4);
                    float4 e1 = *(const float4*)(eaS + (long long)(p + 1) * 4);
                    float4 e2 = *(const float4*)(eaS + (long long)(p + 2) * 4);
                    float4 e3 = *(const float4*)(eaS + (long long)(p + 3) * 4);
                    #pragma unroll
                    for (int j = 0; j < 8; ++j) {
                        float m0 = b2f(pv0[j]) + bv8[j];
                        m0 = fmaf(e0.x, wea[0][j], m0); m0 = fmaf(e0.y, wea[1][j], m0);
                        m0 = fmaf(e0.z, wea[2][j], m0); m0 = fmaf(e0.w, wea[3][j], m0);
                        float m1 = b2f(pv1[j]) + bv8[j];
                        m1 = fmaf(e1.x, wea[0][j], m1); m1 = fmaf(e1.y, wea[1][j], m1);
                        m1 = fmaf(e1.z, wea[2][j], m1); m1 = fmaf(e1.w, wea[3][j], m1);
                        float m2 = b2f(pv2[j]) + bv8[j];
                        m2 = fmaf(e2.x, wea[0][j], m2); m2 = fmaf(e2.y, wea[1][j], m2);
                        m2 = fmaf(e2.z, wea[2][j], m2); m2 = fmaf(e2.w, wea[3][j], m2);
                        float m3 = b2f(pv3[j]) + bv8[j];
                        m3 = fmaf(e3.x, wea[0][j], m3); m3 = fmaf(e3.y, wea[1][j], m3);
                        m3 = fmaf(e3.z, wea[2][j], m3); m3 = fmaf(e3.w, wea[3][j], m3);
                        acc[j] += (fmaxf(m0, 0.f) + fmaxf(m1, 0.f)) + (fmaxf(m2, 0.f) + fmaxf(m3, 0.f));
                    }
                }
                for (; p < e; ++p) {
                    int src = srcS[p];
                    u16x8 pv = *(const u16x8*)(Pread + (long long)src * HD + cg * 8);
                    float4 e4 = *(const float4*)(eaS + (long long)p * 4);
                    #pragma unroll
                    for (int j = 0; j < 8; ++j) {
                        float m = b2f(pv[j]) + bv8[j];
                        m = fmaf(e4.x, wea[0][j], m);
                        m = fmaf(e4.y, wea[1][j], m);
                        m = fmaf(e4.z, wea[2][j], m);
                        m = fmaf(e4.w, wea[3][j], m);
                        acc[j] += fmaxf(m, 0.f);
                    }
                }
            }
            u16x8 o;
            #pragma unroll
            for (int j = 0; j < 8; ++j) o[j] = f2b(acc[j]);
            *(u16x8*)&CsAgg[(cg * 128 + nl) * 8] = o;
        }
        __syncthreads();
    }

    // ---- phase B: node GEMM
    const int srow = t >> 1, half = t & 1;
    int gr  = bRow + srow;
    int grc = gr < M ? gr : M - 1;
    const unsigned short* p1 = seg1 ? seg1 + (long long)grc * s1 + xoff : nullptr;
    const unsigned short* pb = WTn + (long long)srow * K;
    const int c0 = half * 2, c1 = half * 2 + 1;

    f32x4 acc[4][4];
    #pragma unroll
    for (int m = 0; m < 4; ++m)
        #pragma unroll
        for (int n = 0; n < 4; ++n) acc[m][n] = f32x4{0.f, 0.f, 0.f, 0.f};

    const int nkt = K >> 5;
    const int nxt = D1 >> 5;
    for (int kt = 0; kt < nkt; ++kt) {
        bool fromX = !EDGE || (kt < nxt);
        if (fromX) {
            int k0 = (kt << 5) + half * 16;
            const u16x8* sp = (const u16x8*)(p1 + k0);
            u16x8 a0 = sp[0], a1 = sp[1];
            *(u16x8*)&As[(c0 * 128 + srow) * 8] = a0;
            *(u16x8*)&As[(c1 * 128 + srow) * 8] = a1;
        }
        const u16x8* bp = (const u16x8*)(pb + (kt << 5) + half * 16);
        u16x8 b0 = bp[0], b1 = bp[1];
        *(u16x8*)&Bs[(c0 * 128 + srow) * 8] = b0;
        *(u16x8*)&Bs[(c1 * 128 + srow) * 8] = b1;
        __syncthreads();

        s16x8 af[4], bfr[4];
        if (EDGE && kt >= nxt) {
            int base = (kt - nxt) * 4 + kb;
            #pragma unroll
            for (int m = 0; m < 4; ++m)
                af[m] = *(const s16x8*)&CsAgg[(base * 128 + wm * 64 + m * 16 + ln) * 8];
        } else {
            #pragma unroll
            for (int m = 0; m < 4; ++m)
                af[m] = *(const s16x8*)&As[(kb * 128 + wm * 64 + m * 16 + ln) * 8];
        }
        #pragma unroll
        for (int n = 0; n < 4; ++n)
            bfr[n] = *(const s16x8*)&Bs[(kb * 128 + wn * 64 + n * 16 + ln) * 8];
        #pragma unroll
        for (int m = 0; m < 4; ++m)
            #pragma unroll
            for (int n = 0; n < 4; ++n)
                acc[m][n] = __builtin_amdgcn_mfma_f32_16x16x32_bf16(af[m], bfr[n], acc[m][n], 0, 0, 0);
        __syncthreads();
    }

    // ---- epilogue 1 (writes Out, and C tile into CsAgg for phase C)
    float bv[4];
    if (ACT && !ADDF) {
        #pragma unroll
        for (int n = 0; n < 4; ++n) bv[n] = bias[wn * 64 + n * 16 + ln];
    }
    #pragma unroll
    for (int m = 0; m < 4; ++m) {
        #pragma unroll
        for (int r = 0; r < 4; ++r) {
            int lrow = wm * 64 + m * 16 + kb * 4 + r;
            int grow = bRow + lrow;
            int gcl  = grow < M ? grow : M - 1;
            unsigned short* op = OutB + (long long)gcl * ostride + ooff;
            const float* ap = ADDF ? addF + (long long)gcl * HD : nullptr;
            #pragma unroll
            for (int n = 0; n < 4; ++n) {
                int col = wn * 64 + n * 16 + ln;
                float v = acc[m][n][r];
                if (ADDF) v += ap[col];
                else if (ACT) v += bv[n];
                if (ACT) v = fmaxf(v, 0.f);
                unsigned short b = f2b(v);
                if (grow < M) op[col] = b;
                if (PROJ || PROJ8) {
                    int cidx = (((wn * 2 + (n >> 1)) * 4 + ((n & 1) << 1) + (ln >> 3)) * 128 + lrow) * 8 + (ln & 7);
                    CsAgg[cidx] = b;
                }
            }
        }
    }

    // ---- phase C: full 128-col projection via MFMA
    if (PROJ) {
        f32x4 acc2[4][4];
        #pragma unroll
        for (int m = 0; m < 4; ++m)
            #pragma unroll
            for (int n = 0; n < 4; ++n) acc2[m][n] = f32x4{0.f, 0.f, 0.f, 0.f};

        const unsigned short* pb2 = WTe + (long long)srow * 128;
        for (int kt = 0; kt < 4; ++kt) {
            const u16x8* bp = (const u16x8*)(pb2 + (kt << 5) + half * 16);
            u16x8 b0 = bp[0], b1 = bp[1];
            *(u16x8*)&Bs[(c0 * 128 + srow) * 8] = b0;
            *(u16x8*)&Bs[(c1 * 128 + srow) * 8] = b1;
            __syncthreads();

            s16x8 af[4], bfr[4];
            #pragma unroll
            for (int m = 0; m < 4; ++m)
                af[m] = *(const s16x8*)&CsAgg[((kt * 4 + kb) * 128 + wm * 64 + m * 16 + ln) * 8];
            #pragma unroll
            for (int n = 0; n < 4; ++n)
                bfr[n] = *(const s16x8*)&Bs[(kb * 128 + wn * 64 + n * 16 + ln) * 8];
            #pragma unroll
            for (int m = 0; m < 4; ++m)
                #pragma unroll
                for (int n = 0; n < 4; ++n)
                    acc2[m][n] = __builtin_amdgcn_mfma_f32_16x16x32_bf16(af[m], bfr[n], acc2[m][n], 0, 0, 0);
            __syncthreads();
        }

        #pragma unroll
        for (int m = 0; m < 4; ++m) {
            #pragma unroll
            for (int r = 0; r < 4; ++r) {
                int grow = bRow + wm * 64 + m * 16 + kb * 4 + r;
                if (grow < M) {
                    unsigned short* op = Pout + (long long)grow * HD;
                    #pragma unroll
                    for (int n = 0; n < 4; ++n)
                        op[wn * 64 + n * 16 + ln] = f2b(acc2[m][n][r]);
                }
            }
        }
    }

    // ---- phase C': 8-col projection via VALU
    if (PROJ8) {
        __syncthreads();
        int row = t >> 1;
        int j0  = (t & 1) * 4;
        int grow = bRow + row;
        float a[4] = {0.f, 0.f, 0.f, 0.f};
        #pragma unroll 4
        for (int kc = 0; kc < 16; ++kc) {
            u16x8 cv = *(const u16x8*)&CsAgg[(kc * 128 + row) * 8];
            #pragma unroll
            for (int kk = 0; kk < 8; ++kk) {
                float f = b2f(cv[kk]);
                #pragma unroll
                for (int j = 0; j < 4; ++j)
                    a[j] = fmaf(f, sWL[(kc * 8 + kk) * 8 + j0 + j], a[j]);
            }
        }
        if (grow < M) {
            float4 o = {a[0], a[1], a[2], a[3]};
            *(float4*)(PLout + (long long)grow * 8 + j0) = o;
        }
    }
}

// ---------------- fused last layer (Hout=8): edge agg + node MLP
__global__ __launch_bounds__(256)
void last_fused(const unsigned short* __restrict__ HC, const float* __restrict__ PL,
                const int* __restrict__ srcS, const int* __restrict__ rowptr,
                const float* __restrict__ eaS,
                const float* __restrict__ WeL, const float* __restrict__ beL,
                const float* __restrict__ WnL, const float* __restrict__ bnL,
                float* __restrict__ out)
{
    __shared__ float sWn[136 * 8];
    __shared__ float aggL[32][8];
    int t = threadIdx.x;
    for (int i = t; i < 136 * 8; i += 256) sWn[i] = WnL[i];
    int nl = t >> 3, j = t & 7;
    int n  = blockIdx.x * 32 + nl;

    float wea[4];
    #pragma unroll
    for (int c = 0; c < 4; ++c) wea[c] = WeL[(HD + c) * 8 + j];
    float bb = beL[j];
    int s = rowptr[n], e = rowptr[n + 1];
    float acc = 0.f;
    int p = s;
    for (; p + 4 <= e; p += 4) {
        int s0 = srcS[p + 0], s1 = srcS[p + 1], s2 = srcS[p + 2], s3 = srcS[p + 3];
        float q0 = PL[(long long)s0 * 8 + j], q1 = PL[(long long)s1 * 8 + j];
        float q2 = PL[(long long)s2 * 8 + j], q3 = PL[(long long)s3 * 8 + j];
        float4 e0 = *(const float4*)(eaS + (long long)(p + 0) * 4);
        float4 e1 = *(const float4*)(eaS + (long long)(p + 1) * 4);
        float4 e2 = *(const float4*)(eaS + (long long)(p + 2) * 4);
        float4 e3 = *(const float4*)(eaS + (long long)(p + 3) * 4);
        float m0 = q0 + bb;
        m0 = fmaf(e0.x, wea[0], m0); m0 = fmaf(e0.y, wea[1], m0);
        m0 = fmaf(e0.z, wea[2], m0); m0 = fmaf(e0.w, wea[3], m0);
        float m1 = q1 + bb;
        m1 = fmaf(e1.x, wea[0], m1); m1 = fmaf(e1.y, wea[1], m1);
        m1 = fmaf(e1.z, wea[2], m1); m1 = fmaf(e1.w, wea[3], m1);
        float m2 = q2 + bb;
        m2 = fmaf(e2.x, wea[0], m2); m2 = fmaf(e2.y, wea[1], m2);
        m2 = fmaf(e2.z, wea[2], m2); m2 = fmaf(e2.w, wea[3], m2);
        float m3 = q3 + bb;
        m3 = fmaf(e3.x, wea[0], m3); m3 = fmaf(e3.y, wea[1], m3);
        m3 = fmaf(e3.z, wea[2], m3); m3 = fmaf(e3.w, wea[3], m3);
        acc += (fmaxf(m0, 0.f) + fmaxf(m1, 0.f)) + (fmaxf(m2, 0.f) + fmaxf(m3, 0.f));
    }
    for (; p < e; ++p) {
        int src = srcS[p];
        float m = PL[(long long)src * 8 + j] + bb;
        float4 e4 = *(const float4*)(eaS + (long long)p * 4);
        m = fmaf(e4.x, wea[0], m);
        m = fmaf(e4.y, wea[1], m);
        m = fmaf(e4.z, wea[2], m);
        m = fmaf(e4.w, wea[3], m);
        acc += fmaxf(m, 0.f);
    }
    aggL[nl][j] = acc;
    __syncthreads();

    float o = bnL[j];
    const unsigned short* xr = HC + (long long)n * HD;
    for (int k8 = 0; k8 < HD / 8; ++k8) {
        u16x8 v = *(const u16x8*)(xr + k8 * 8);
        #pragma unroll
        for (int c = 0; c < 8; ++c)
            o = fmaf(b2f(v[c]), sWn[(k8 * 8 + c) * 8 + j], o);
    }
    #pragma unroll
    for (int c = 0; c < 8; ++c)
        o = fmaf(aggL[nl][c], sWn[(HD + c) * 8 + j], o);
    out[(long long)n * 8 + j] = fmaxf(o, 0.f);
}

extern "C" void kernel_launch(void* const* d_in, const int* in_sizes, int n_in,
                              void* d_out, int out_size, void* d_ws, size_t ws_size,
                              hipStream_t stream) {
    const float* x    = (const float*)d_in[0];
    const int*   ei   = (const int*)d_in[1];
    const float* ea   = (const float*)d_in[2];
    const float* We1  = (const float*)d_in[3];
    const float* be1  = (const float*)d_in[4];
    const float* Wn1  = (const float*)d_in[5];
    const float* bn1  = (const float*)d_in[6];
    const float* WeM  = (const float*)d_in[7];
    const float* beM  = (const float*)d_in[8];
    const float* WnM  = (const float*)d_in[9];
    const float* bnM  = (const float*)d_in[10];
    const float* WeC  = (const float*)d_in[11];
    const float* beC  = (const float*)d_in[12];
    const float* WnC  = (const float*)d_in[13];
    const float* bnC  = (const float*)d_in[14];
    const float* WeL  = (const float*)d_in[15];
    const float* beL  = (const float*)d_in[16];
    const float* WnL  = (const float*)d_in[17];
    const float* bnL  = (const float*)d_in[18];

    char* w = (char*)d_ws;
    auto alloc = [&](size_t bytes) -> char* {
        char* p = w; w += (bytes + 255) & ~(size_t)255; return p;
    };
    int*            cnt    = (int*)           alloc((size_t)NN * 4);
    int*            cursor = (int*)           alloc((size_t)NN * 4);
    int*            rowptr = (int*)           alloc((size_t)(NN + 1) * 4);
    int*            bsum   = (int*)           alloc((size_t)256 * 4);
    int*            boffs  = (int*)           alloc((size_t)256 * 4);
    int*            srcS   = (int*)           alloc((size_t)NE * 4);
    float*          eaS    = (float*)         alloc((size_t)NE * 4 * 4);
    unsigned short* PA     = (unsigned short*)alloc((size_t)NN * HD * 2);
    unsigned short* PB     = (unsigned short*)alloc((size_t)NN * HD * 2);
    float*          B1     = (float*)         alloc((size_t)NN * HD * 4);
    unsigned short* XS     = (unsigned short*)alloc((size_t)NN * 7 * HD * 2);
    unsigned short* HC     = (unsigned short*)alloc((size_t)NN * HD * 2);
    float*          PL     = (float*)         alloc((size_t)NN * 8 * 4);
    unsigned short* WTn1   = (unsigned short*)alloc((size_t)HD * 128 * 2);
    unsigned short* WTeM   = (unsigned short*)alloc((size_t)6 * HD * 128 * 2);
    unsigned short* WTnM   = (unsigned short*)alloc((size_t)6 * HD * 256 * 2);
    unsigned short* WTeC   = (unsigned short*)alloc((size_t)HD * 896 * 2);
    unsigned short* WTnC   = (unsigned short*)alloc((size_t)HD * 1024 * 2);
    float* out = (float*)d_out;

    // --- CSR build
    zero_cnt<<<NBLK, 256, 0, stream>>>(cnt);
    hist_kernel<<<(NE + 255) / 256, 256, 0, stream>>>(ei, cnt);
    scan1_kernel<<<NBLK, 256, 0, stream>>>(cnt, rowptr, bsum, cursor);
    scan2_kernel<<<1, 256, 0, stream>>>(bsum, boffs);
    scan3_kernel<<<NBLK, 256, 0, stream>>>(rowptr, boffs);
    scatter_kernel<<<(NE + 255) / 256, 256, 0, stream>>>(ei, ea, rowptr, cursor, srcS, eaS);

    // --- weight transposes (one dispatch)
    cvt_all<<<dim3(512, 15), 256, 0, stream>>>(WeM, WnM, WeC, WnC, Wn1,
                                               WTeM, WTnM, WTeC, WTnC, WTn1);

    const int ngrid = (NN + 127) / 128;    // 157

    // --- layer 1: P + B1; fused (edge + node K=128 via AggS + proj -> PB)
    proj8_dual<<<NN * HD / 256, 256, 0, stream>>>(x, We1, Wn1, bn1, PA, B1);
    mfma_fused<true, true, true, true, false><<<ngrid, 256, 0, stream>>>(
        nullptr, 0, 0, 0, PA, srcS, rowptr, eaS, We1 + 8 * HD, be1,
        WTn1, nullptr, B1, XS, 7 * HD, 0, WTeM, PB, nullptr, nullptr, NN, 128);

    // --- layers 2..6: fused (edge + node K=256 + proj), P alternates
    for (int i = 0; i < 5; ++i) {
        const unsigned short* Pr = (i % 2 == 0) ? PB : PA;
        unsigned short*       Pw = (i % 2 == 0) ? PA : PB;
        mfma_fused<true, true, false, true, false><<<ngrid, 256, 0, stream>>>(
            XS, 7 * HD, i * HD, HD, Pr, srcS, rowptr, eaS,
            WeM + (size_t)i * 132 * HD + (size_t)128 * HD, beM + i * HD,
            WTnM + (size_t)i * HD * 256, bnM + i * HD, nullptr,
            XS, 7 * HD, (i + 1) * HD, WTeM + (size_t)(i + 1) * HD * 128, Pw,
            nullptr, nullptr, NN, 256);
    }

    // --- layer 7: fused (edge + node), no proj. i=5 reads PB(i even pattern): after
    // L2..L6 (5 iters) last write was Pw of i=4 -> PA. So L7 reads PA.
    mfma_fused<true, true, false, false, false><<<ngrid, 256, 0, stream>>>(
        XS, 7 * HD, 5 * HD, HD, PA, srcS, rowptr, eaS,
        WeM + (size_t)5 * 132 * HD + (size_t)128 * HD, beM + 5 * HD,
        WTnM + (size_t)5 * HD * 256, bnM + 5 * HD, nullptr,
        XS, 7 * HD, 6 * HD, nullptr, nullptr, nullptr, nullptr, NN, 256);

    // --- concat layer: proj (K=896) -> PB; fused node (K=1024) + PL projection
    mfma_fused<false, false, false, false, false><<<ngrid, 256, 0, stream>>>(
        XS, 7 * HD, 0, 7 * HD, nullptr, nullptr, nullptr, nullptr, nullptr, nullptr,
        WTeC, nullptr, nullptr, PB, HD, 0, nullptr, nullptr, nullptr, nullptr, NN, 896);
    mfma_fused<true, true, false, false, true><<<ngrid, 256, 0, stream>>>(
        XS, 7 * HD, 0, 7 * HD, PB, srcS, rowptr, eaS,
        WeC + (size_t)896 * HD, beC,
        WTnC, bnC, nullptr, HC, HD, 0, nullptr, nullptr, WeL, PL, NN, 1024);

    // --- last layer (Hout=8): fused agg + node MLP
    last_fused<<<NN / 32, 256, 0, stream>>>(HC, PL, srcS, rowptr, eaS,
                                            WeL, beL, WnL, bnL, out);
}

// Round 13
// 446.496 us; speedup vs baseline: 1.4888x; 1.4888x over previous
//
#include <hip/hip_runtime.h>

#define NN 20000
#define NE 320000
#define HD 128
#define NBLK ((NN + 255) / 256)   // 79

typedef short     s16x8 __attribute__((ext_vector_type(8)));
typedef unsigned short u16x8 __attribute__((ext_vector_type(8)));
typedef float     f32x4 __attribute__((ext_vector_type(4)));

__device__ __forceinline__ float b2f(unsigned short u) {
    union { unsigned int i; float f; } c; c.i = ((unsigned int)u) << 16; return c.f;
}
__device__ __forceinline__ unsigned short f2b(float f) {
    union { float f; unsigned int i; } c; c.f = f;
    unsigned int x = c.i + 0x7FFFu + ((c.i >> 16) & 1u);
    return (unsigned short)(x >> 16);
}

// ---------------- CSR build ----------------
__global__ void zero_cnt(int* __restrict__ cnt) {
    int i = blockIdx.x * 256 + threadIdx.x;
    if (i < NN) cnt[i] = 0;
}

__global__ void hist_kernel(const int* __restrict__ ei, int* __restrict__ cnt) {
    int e = blockIdx.x * 256 + threadIdx.x;
    if (e < NE) atomicAdd(&cnt[ei[NE + e]], 1);
}

__global__ void scan1_kernel(const int* __restrict__ cnt, int* __restrict__ rowptr,
                             int* __restrict__ bsum, int* __restrict__ cursor) {
    __shared__ int s[256];
    int t = threadIdx.x;
    int i = blockIdx.x * 256 + t;
    if (i < NN) cursor[i] = 0;
    int v = (i < NN) ? cnt[i] : 0;
    s[t] = v; __syncthreads();
    #pragma unroll
    for (int off = 1; off < 256; off <<= 1) {
        int add = (t >= off) ? s[t - off] : 0;
        __syncthreads();
        s[t] += add;
        __syncthreads();
    }
    if (i < NN) rowptr[i] = s[t] - v;
    if (t == 255) bsum[blockIdx.x] = s[t];
}

__global__ void scan2_kernel(int* __restrict__ bsum, int* __restrict__ boffs) {
    __shared__ int s[256];
    int t = threadIdx.x;
    int v = (t < NBLK) ? bsum[t] : 0;
    s[t] = v; __syncthreads();
    #pragma unroll
    for (int off = 1; off < 256; off <<= 1) {
        int add = (t >= off) ? s[t - off] : 0;
        __syncthreads();
        s[t] += add;
        __syncthreads();
    }
    if (t < NBLK) boffs[t] = s[t] - v;
}

__global__ void scan3_kernel(int* __restrict__ rowptr, const int* __restrict__ boffs) {
    int i = blockIdx.x * 256 + threadIdx.x;
    if (i < NN) rowptr[i] += boffs[blockIdx.x];
    if (i == 0) rowptr[NN] = NE;
}

__global__ void scatter_kernel(const int* __restrict__ ei, const float* __restrict__ ea,
                               const int* __restrict__ rowptr, int* __restrict__ cursor,
                               int* __restrict__ srcS, float* __restrict__ eaS) {
    int e = blockIdx.x * 256 + threadIdx.x;
    if (e >= NE) return;
    int d = ei[NE + e];
    int pos = rowptr[d] + atomicAdd(&cursor[d], 1);
    srcS[pos] = ei[e];
    *(float4*)(eaS + (long long)pos * 4) = *(const float4*)(ea + (long long)e * 4);
}

// ---------------- all weight transposes in one dispatch (grid.y = 15)
__global__ void cvt_all(const float* __restrict__ WeM, const float* __restrict__ WnM,
                        const float* __restrict__ WeC, const float* __restrict__ WnC,
                        const float* __restrict__ Wn1,
                        unsigned short* __restrict__ WTeM, unsigned short* __restrict__ WTnM,
                        unsigned short* __restrict__ WTeC, unsigned short* __restrict__ WTnC,
                        unsigned short* __restrict__ WTn1) {
    int y = blockIdx.y;
    const float* W; unsigned short* WT; int K;
    if (y < 6)       { W = WeM + (size_t)y * 132 * HD;       WT = WTeM + (size_t)y * HD * 128; K = 128; }
    else if (y < 12) { int i = y - 6;
                       W = WnM + (size_t)i * 256 * HD;       WT = WTnM + (size_t)i * HD * 256; K = 256; }
    else if (y == 12){ W = WeC;                              WT = WTeC;                        K = 896; }
    else if (y == 13){ W = WnC;                              WT = WTnC;                        K = 1024; }
    else             { W = Wn1 + 8 * HD;                     WT = WTn1;                        K = 128; }
    int tid = blockIdx.x * 256 + threadIdx.x;
    if (tid >= K * HD) return;
    int n = tid & (HD - 1), k = tid >> 7;
    WT[(size_t)n * K + k] = f2b(W[(size_t)k * HD + n]);
}

// ---------------- layer-1 dual projection
__global__ void proj8_dual(const float* __restrict__ x,
                           const float* __restrict__ We1, const float* __restrict__ Wn1,
                           const float* __restrict__ bn1,
                           unsigned short* __restrict__ P, float* __restrict__ B1) {
    int t = blockIdx.x * 256 + threadIdx.x;
    int n = t >> 7, j = t & 127;
    const float* xr = x + (long long)n * 8;
    float a = 0.f, b = bn1[j];
    #pragma unroll
    for (int k = 0; k < 8; ++k) {
        float xv = xr[k];
        a = fmaf(xv, We1[k * HD + j], a);
        b = fmaf(xv, Wn1[k * HD + j], b);
    }
    P[t]  = f2b(a);
    B1[t] = b;
}

// ---------------- fused edge pass, 8-way unrolled gather pipeline
__global__ __launch_bounds__(256)
void edge_agg(const unsigned short* __restrict__ P,
              const int* __restrict__ srcS, const int* __restrict__ rowptr,
              const float* __restrict__ eaS,
              const float* __restrict__ Wea,
              const float* __restrict__ bias,
              unsigned short* __restrict__ AggB)
{
    int t  = threadIdx.x;
    int n  = blockIdx.x * 16 + (t >> 4);
    int cg = t & 15;
    float wea[4][8], bv[8];
    #pragma unroll
    for (int c = 0; c < 4; ++c)
        #pragma unroll
        for (int j = 0; j < 8; ++j) wea[c][j] = Wea[c * HD + cg * 8 + j];
    #pragma unroll
    for (int j = 0; j < 8; ++j) bv[j] = bias[cg * 8 + j];

    int s = rowptr[n], e = rowptr[n + 1];
    float acc[8];
    #pragma unroll
    for (int j = 0; j < 8; ++j) acc[j] = 0.f;

    int p = s;
    for (; p + 8 <= e; p += 8) {
        int   si[8];
        u16x8 pv[8];
        float4 ev[8];
        #pragma unroll
        for (int q = 0; q < 8; ++q) si[q] = srcS[p + q];
        #pragma unroll
        for (int q = 0; q < 8; ++q) pv[q] = *(const u16x8*)(P + (long long)si[q] * HD + cg * 8);
        #pragma unroll
        for (int q = 0; q < 8; ++q) ev[q] = *(const float4*)(eaS + (long long)(p + q) * 4);
        #pragma unroll
        for (int q = 0; q < 8; ++q) {
            #pragma unroll
            for (int j = 0; j < 8; ++j) {
                float m = b2f(pv[q][j]) + bv[j];
                m = fmaf(ev[q].x, wea[0][j], m);
                m = fmaf(ev[q].y, wea[1][j], m);
                m = fmaf(ev[q].z, wea[2][j], m);
                m = fmaf(ev[q].w, wea[3][j], m);
                acc[j] += fmaxf(m, 0.f);
            }
        }
    }
    for (; p < e; ++p) {
        int src = srcS[p];
        u16x8 pv = *(const u16x8*)(P + (long long)src * HD + cg * 8);
        float4 e4 = *(const float4*)(eaS + (long long)p * 4);
        #pragma unroll
        for (int j = 0; j < 8; ++j) {
            float m = b2f(pv[j]) + bv[j];
            m = fmaf(e4.x, wea[0][j], m);
            m = fmaf(e4.y, wea[1][j], m);
            m = fmaf(e4.z, wea[2][j], m);
            m = fmaf(e4.w, wea[3][j], m);
            acc[j] += fmaxf(m, 0.f);
        }
    }
    u16x8 o;
    #pragma unroll
    for (int j = 0; j < 8; ++j) o[j] = f2b(acc[j]);
    *(u16x8*)(AggB + (long long)n * HD + cg * 8) = o;
}

// ---------------- MFMA layer kernel, BM=128, 4 waves (2x2), N=128.
// Stage 1: C = [relu](A @ WTn [+ bias | + addF]); C -> OutB and (PROJ|PROJ8) LDS Cs.
// Stage 2 PROJ : P = C @ WTe (full 128 cols, MFMA) -> Pout bf16.
// Stage 2 PROJ8: PL = C @ WeLf[:128] (8 cols, VALU) -> PLout fp32.
template<bool ACT, bool ADDF, bool PROJ, bool PROJ8>
__global__ __launch_bounds__(256)
void mfma_np(const unsigned short* __restrict__ seg1, long long s1, int xoff, int D1,
             const unsigned short* __restrict__ seg2, long long s2,
             const unsigned short* __restrict__ WTn, const float* __restrict__ bias,
             const float* __restrict__ addF,
             unsigned short* __restrict__ OutB, long long ostride, int ooff,
             const unsigned short* __restrict__ WTe,
             unsigned short* __restrict__ Pout,
             const float* __restrict__ WeLf, float* __restrict__ PLout,
             int M, int K)
{
    __shared__ unsigned short As[4 * 128 * 8];
    __shared__ unsigned short Bs[4 * 128 * 8];
    __shared__ unsigned short Cs[(PROJ || PROJ8) ? 16 * 128 * 8 : 8];
    __shared__ float sWL[PROJ8 ? 128 * 8 : 1];

    const int t    = threadIdx.x;
    const int lane = t & 63;
    const int wid  = t >> 6;
    const int wm   = wid >> 1, wn = wid & 1;
    const int ln   = lane & 15, kb = lane >> 4;
    const int bRow = blockIdx.x * 128;

    if (PROJ8) {
        for (int i = t; i < 128 * 8; i += 256) sWL[i] = WeLf[i];
    }

    const int srow = t >> 1, half = t & 1;
    int gr  = bRow + srow;
    int grc = gr < M ? gr : M - 1;
    const unsigned short* p1 = seg1 + (long long)grc * s1 + xoff;
    const unsigned short* p2 = seg2 ? seg2 + (long long)grc * s2 : nullptr;
    const unsigned short* pb = WTn + (long long)srow * K;
    const int c0 = half * 2, c1 = half * 2 + 1;

    f32x4 acc[4][4];
    #pragma unroll
    for (int m = 0; m < 4; ++m)
        #pragma unroll
        for (int n = 0; n < 4; ++n) acc[m][n] = f32x4{0.f, 0.f, 0.f, 0.f};

    const int nkt = K >> 5;
    for (int kt = 0; kt < nkt; ++kt) {
        int k0 = (kt << 5) + half * 16;
        const u16x8* sp = (k0 + 16 <= D1) ? (const u16x8*)(p1 + k0)
                                          : (const u16x8*)(p2 + (k0 - D1));
        u16x8 a0 = sp[0], a1 = sp[1];
        *(u16x8*)&As[(c0 * 128 + srow) * 8] = a0;
        *(u16x8*)&As[(c1 * 128 + srow) * 8] = a1;
        const u16x8* bp = (const u16x8*)(pb + (kt << 5) + half * 16);
        u16x8 b0 = bp[0], b1 = bp[1];
        *(u16x8*)&Bs[(c0 * 128 + srow) * 8] = b0;
        *(u16x8*)&Bs[(c1 * 128 + srow) * 8] = b1;
        __syncthreads();

        s16x8 af[4], bfr[4];
        #pragma unroll
        for (int m = 0; m < 4; ++m)
            af[m] = *(const s16x8*)&As[(kb * 128 + wm * 64 + m * 16 + ln) * 8];
        #pragma unroll
        for (int n = 0; n < 4; ++n)
            bfr[n] = *(const s16x8*)&Bs[(kb * 128 + wn * 64 + n * 16 + ln) * 8];
        #pragma unroll
        for (int m = 0; m < 4; ++m)
            #pragma unroll
            for (int n = 0; n < 4; ++n)
                acc[m][n] = __builtin_amdgcn_mfma_f32_16x16x32_bf16(af[m], bfr[n], acc[m][n], 0, 0, 0);
        __syncthreads();
    }

    // ---- epilogue 1
    float bv[4];
    if (ACT && !ADDF) {
        #pragma unroll
        for (int n = 0; n < 4; ++n) bv[n] = bias[wn * 64 + n * 16 + ln];
    }
    #pragma unroll
    for (int m = 0; m < 4; ++m) {
        #pragma unroll
        for (int r = 0; r < 4; ++r) {
            int lrow = wm * 64 + m * 16 + kb * 4 + r;
            int grow = bRow + lrow;
            int gcl  = grow < M ? grow : M - 1;
            unsigned short* op = OutB + (long long)gcl * ostride + ooff;
            const float* ap = ADDF ? addF + (long long)gcl * HD : nullptr;
            #pragma unroll
            for (int n = 0; n < 4; ++n) {
                int col = wn * 64 + n * 16 + ln;
                float v = acc[m][n][r];
                if (ADDF) v += ap[col];
                else if (ACT) v += bv[n];
                if (ACT) v = fmaxf(v, 0.f);
                unsigned short b = f2b(v);
                if (grow < M) op[col] = b;
                if (PROJ || PROJ8) {
                    int cidx = (((wn * 2 + (n >> 1)) * 4 + ((n & 1) << 1) + (ln >> 3)) * 128 + lrow) * 8 + (ln & 7);
                    Cs[cidx] = b;
                }
            }
        }
    }

    // ---- stage 2 (full 128-col projection via MFMA)
    if (PROJ) {
        f32x4 acc2[4][4];
        #pragma unroll
        for (int m = 0; m < 4; ++m)
            #pragma unroll
            for (int n = 0; n < 4; ++n) acc2[m][n] = f32x4{0.f, 0.f, 0.f, 0.f};

        const unsigned short* pb2 = WTe + (long long)srow * 128;
        for (int kt = 0; kt < 4; ++kt) {
            const u16x8* bp = (const u16x8*)(pb2 + (kt << 5) + half * 16);
            u16x8 b0 = bp[0], b1 = bp[1];
            *(u16x8*)&Bs[(c0 * 128 + srow) * 8] = b0;
            *(u16x8*)&Bs[(c1 * 128 + srow) * 8] = b1;
            __syncthreads();

            s16x8 af[4], bfr[4];
            #pragma unroll
            for (int m = 0; m < 4; ++m)
                af[m] = *(const s16x8*)&Cs[((kt * 4 + kb) * 128 + wm * 64 + m * 16 + ln) * 8];
            #pragma unroll
            for (int n = 0; n < 4; ++n)
                bfr[n] = *(const s16x8*)&Bs[(kb * 128 + wn * 64 + n * 16 + ln) * 8];
            #pragma unroll
            for (int m = 0; m < 4; ++m)
                #pragma unroll
                for (int n = 0; n < 4; ++n)
                    acc2[m][n] = __builtin_amdgcn_mfma_f32_16x16x32_bf16(af[m], bfr[n], acc2[m][n], 0, 0, 0);
            __syncthreads();
        }

        #pragma unroll
        for (int m = 0; m < 4; ++m) {
            #pragma unroll
            for (int r = 0; r < 4; ++r) {
                int grow = bRow + wm * 64 + m * 16 + kb * 4 + r;
                if (grow < M) {
                    unsigned short* op = Pout + (long long)grow * HD;
                    #pragma unroll
                    for (int n = 0; n < 4; ++n)
                        op[wn * 64 + n * 16 + ln] = f2b(acc2[m][n][r]);
                }
            }
        }
    }

    // ---- stage 2 (8-col projection via VALU): PL = C @ WeL[:128]
    if (PROJ8) {
        __syncthreads();
        int row = t >> 1;
        int j0  = (t & 1) * 4;
        int grow = bRow + row;
        float a[4] = {0.f, 0.f, 0.f, 0.f};
        #pragma unroll 4
        for (int kc = 0; kc < 16; ++kc) {
            u16x8 cv = *(const u16x8*)&Cs[(kc * 128 + row) * 8];
            #pragma unroll
            for (int kk = 0; kk < 8; ++kk) {
                float f = b2f(cv[kk]);
                #pragma unroll
                for (int j = 0; j < 4; ++j)
                    a[j] = fmaf(f, sWL[(kc * 8 + kk) * 8 + j0 + j], a[j]);
            }
        }
        if (grow < M) {
            float4 o = {a[0], a[1], a[2], a[3]};
            *(float4*)(PLout + (long long)grow * 8 + j0) = o;
        }
    }
}

// ---------------- fused last layer (Hout=8): edge agg + node MLP
__global__ __launch_bounds__(256)
void last_fused(const unsigned short* __restrict__ HC, const float* __restrict__ PL,
                const int* __restrict__ srcS, const int* __restrict__ rowptr,
                const float* __restrict__ eaS,
                const float* __restrict__ WeL, const float* __restrict__ beL,
                const float* __restrict__ WnL, const float* __restrict__ bnL,
                float* __restrict__ out)
{
    __shared__ float sWn[136 * 8];
    __shared__ float aggL[32][8];
    int t = threadIdx.x;
    for (int i = t; i < 136 * 8; i += 256) sWn[i] = WnL[i];
    int nl = t >> 3, j = t & 7;
    int n  = blockIdx.x * 32 + nl;

    float wea[4];
    #pragma unroll
    for (int c = 0; c < 4; ++c) wea[c] = WeL[(HD + c) * 8 + j];
    float bb = beL[j];
    int s = rowptr[n], e = rowptr[n + 1];
    float acc = 0.f;
    int p = s;
    for (; p + 4 <= e; p += 4) {
        int s0 = srcS[p + 0], s1 = srcS[p + 1], s2 = srcS[p + 2], s3 = srcS[p + 3];
        float q0 = PL[(long long)s0 * 8 + j], q1 = PL[(long long)s1 * 8 + j];
        float q2 = PL[(long long)s2 * 8 + j], q3 = PL[(long long)s3 * 8 + j];
        float4 e0 = *(const float4*)(eaS + (long long)(p + 0) * 4);
        float4 e1 = *(const float4*)(eaS + (long long)(p + 1) * 4);
        float4 e2 = *(const float4*)(eaS + (long long)(p + 2) * 4);
        float4 e3 = *(const float4*)(eaS + (long long)(p + 3) * 4);
        float m0 = q0 + bb;
        m0 = fmaf(e0.x, wea[0], m0); m0 = fmaf(e0.y, wea[1], m0);
        m0 = fmaf(e0.z, wea[2], m0); m0 = fmaf(e0.w, wea[3], m0);
        float m1 = q1 + bb;
        m1 = fmaf(e1.x, wea[0], m1); m1 = fmaf(e1.y, wea[1], m1);
        m1 = fmaf(e1.z, wea[2], m1); m1 = fmaf(e1.w, wea[3], m1);
        float m2 = q2 + bb;
        m2 = fmaf(e2.x, wea[0], m2); m2 = fmaf(e2.y, wea[1], m2);
        m2 = fmaf(e2.z, wea[2], m2); m2 = fmaf(e2.w, wea[3], m2);
        float m3 = q3 + bb;
        m3 = fmaf(e3.x, wea[0], m3); m3 = fmaf(e3.y, wea[1], m3);
        m3 = fmaf(e3.z, wea[2], m3); m3 = fmaf(e3.w, wea[3], m3);
        acc += (fmaxf(m0, 0.f) + fmaxf(m1, 0.f)) + (fmaxf(m2, 0.f) + fmaxf(m3, 0.f));
    }
    for (; p < e; ++p) {
        int src = srcS[p];
        float m = PL[(long long)src * 8 + j] + bb;
        float4 e4 = *(const float4*)(eaS + (long long)p * 4);
        m = fmaf(e4.x, wea[0], m);
        m = fmaf(e4.y, wea[1], m);
        m = fmaf(e4.z, wea[2], m);
        m = fmaf(e4.w, wea[3], m);
        acc += fmaxf(m, 0.f);
    }
    aggL[nl][j] = acc;
    __syncthreads();

    float o = bnL[j];
    const unsigned short* xr = HC + (long long)n * HD;
    for (int k8 = 0; k8 < HD / 8; ++k8) {
        u16x8 v = *(const u16x8*)(xr + k8 * 8);
        #pragma unroll
        for (int c = 0; c < 8; ++c)
            o = fmaf(b2f(v[c]), sWn[(k8 * 8 + c) * 8 + j], o);
    }
    #pragma unroll
    for (int c = 0; c < 8; ++c)
        o = fmaf(aggL[nl][c], sWn[(HD + c) * 8 + j], o);
    out[(long long)n * 8 + j] = fmaxf(o, 0.f);
}

extern "C" void kernel_launch(void* const* d_in, const int* in_sizes, int n_in,
                              void* d_out, int out_size, void* d_ws, size_t ws_size,
                              hipStream_t stream) {
    const float* x    = (const float*)d_in[0];
    const int*   ei   = (const int*)d_in[1];
    const float* ea   = (const float*)d_in[2];
    const float* We1  = (const float*)d_in[3];
    const float* be1  = (const float*)d_in[4];
    const float* Wn1  = (const float*)d_in[5];
    const float* bn1  = (const float*)d_in[6];
    const float* WeM  = (const float*)d_in[7];
    const float* beM  = (const float*)d_in[8];
    const float* WnM  = (const float*)d_in[9];
    const float* bnM  = (const float*)d_in[10];
    const float* WeC  = (const float*)d_in[11];
    const float* beC  = (const float*)d_in[12];
    const float* WnC  = (const float*)d_in[13];
    const float* bnC  = (const float*)d_in[14];
    const float* WeL  = (const float*)d_in[15];
    const float* beL  = (const float*)d_in[16];
    const float* WnL  = (const float*)d_in[17];
    const float* bnL  = (const float*)d_in[18];

    char* w = (char*)d_ws;
    auto alloc = [&](size_t bytes) -> char* {
        char* p = w; w += (bytes + 255) & ~(size_t)255; return p;
    };
    int*            cnt    = (int*)           alloc((size_t)NN * 4);
    int*            cursor = (int*)           alloc((size_t)NN * 4);
    int*            rowptr = (int*)           alloc((size_t)(NN + 1) * 4);
    int*            bsum   = (int*)           alloc((size_t)256 * 4);
    int*            boffs  = (int*)           alloc((size_t)256 * 4);
    int*            srcS   = (int*)           alloc((size_t)NE * 4);
    float*          eaS    = (float*)         alloc((size_t)NE * 4 * 4);
    unsigned short* Pbuf   = (unsigned short*)alloc((size_t)NN * HD * 2);
    float*          B1     = (float*)         alloc((size_t)NN * HD * 4);
    unsigned short* XS     = (unsigned short*)alloc((size_t)NN * 7 * HD * 2);
    unsigned short* HC     = (unsigned short*)alloc((size_t)NN * HD * 2);
    unsigned short* AggB   = (unsigned short*)alloc((size_t)NN * HD * 2);
    float*          PL     = (float*)         alloc((size_t)NN * 8 * 4);
    unsigned short* WTn1   = (unsigned short*)alloc((size_t)HD * 128 * 2);
    unsigned short* WTeM   = (unsigned short*)alloc((size_t)6 * HD * 128 * 2);
    unsigned short* WTnM   = (unsigned short*)alloc((size_t)6 * HD * 256 * 2);
    unsigned short* WTeC   = (unsigned short*)alloc((size_t)HD * 896 * 2);
    unsigned short* WTnC   = (unsigned short*)alloc((size_t)HD * 1024 * 2);
    float* out = (float*)d_out;

    // --- CSR build
    zero_cnt<<<NBLK, 256, 0, stream>>>(cnt);
    hist_kernel<<<(NE + 255) / 256, 256, 0, stream>>>(ei, cnt);
    scan1_kernel<<<NBLK, 256, 0, stream>>>(cnt, rowptr, bsum, cursor);
    scan2_kernel<<<1, 256, 0, stream>>>(bsum, boffs);
    scan3_kernel<<<NBLK, 256, 0, stream>>>(rowptr, boffs);
    scatter_kernel<<<(NE + 255) / 256, 256, 0, stream>>>(ei, ea, rowptr, cursor, srcS, eaS);

    // --- weight transposes (one dispatch)
    cvt_all<<<dim3(512, 15), 256, 0, stream>>>(WeM, WnM, WeC, WnC, Wn1,
                                               WTeM, WTnM, WTeC, WTnC, WTn1);

    const int ngrid = (NN + 127) / 128;    // 157
    const int agrid = NN / 16;             // 1250

    // --- layer 1: P + B1; edge; fused node+proj(L2 edge weights)
    proj8_dual<<<NN * HD / 256, 256, 0, stream>>>(x, We1, Wn1, bn1, Pbuf, B1);
    edge_agg<<<agrid, 256, 0, stream>>>(Pbuf, srcS, rowptr, eaS, We1 + 8 * HD, be1, AggB);
    mfma_np<true, true, true, false><<<ngrid, 256, 0, stream>>>(
        AggB, HD, 0, HD, nullptr, 0, WTn1, nullptr, B1,
        XS, 7 * HD, 0, WTeM, Pbuf, nullptr, nullptr, NN, 128);

    // --- layers 2..6: edge; fused node+proj(next edge weights)
    for (int i = 0; i < 5; ++i) {
        edge_agg<<<agrid, 256, 0, stream>>>(Pbuf, srcS, rowptr, eaS,
                                            WeM + (size_t)i * 132 * HD + (size_t)128 * HD,
                                            beM + i * HD, AggB);
        mfma_np<true, false, true, false><<<ngrid, 256, 0, stream>>>(
            XS, 7 * HD, i * HD, HD, AggB, HD,
            WTnM + (size_t)i * HD * 256, bnM + i * HD, nullptr,
            XS, 7 * HD, (i + 1) * HD, WTeM + (size_t)(i + 1) * HD * 128, Pbuf,
            nullptr, nullptr, NN, 256);
    }

    // --- layer 7: edge; node only
    edge_agg<<<agrid, 256, 0, stream>>>(Pbuf, srcS, rowptr, eaS,
                                        WeM + (size_t)5 * 132 * HD + (size_t)128 * HD,
                                        beM + 5 * HD, AggB);
    mfma_np<true, false, false, false><<<ngrid, 256, 0, stream>>>(
        XS, 7 * HD, 5 * HD, HD, AggB, HD,
        WTnM + (size_t)5 * HD * 256, bnM + 5 * HD, nullptr,
        XS, 7 * HD, 6 * HD, nullptr, nullptr, nullptr, nullptr, NN, 256);

    // --- concat layer: proj (K=896); edge; node (K=1024) fused with PL projection
    mfma_np<false, false, false, false><<<ngrid, 256, 0, stream>>>(
        XS, 7 * HD, 0, 7 * HD, nullptr, 0, WTeC, nullptr, nullptr,
        Pbuf, HD, 0, nullptr, nullptr, nullptr, nullptr, NN, 896);
    edge_agg<<<agrid, 256, 0, stream>>>(Pbuf, srcS, rowptr, eaS,
                                        WeC + (size_t)896 * HD, beC, AggB);
    mfma_np<true, false, false, true><<<ngrid, 256, 0, stream>>>(
        XS, 7 * HD, 0, 7 * HD, AggB, HD, WTnC, bnC, nullptr,
        HC, HD, 0, nullptr, nullptr, WeL, PL, NN, 1024);

    // --- last layer (Hout=8): fused agg + node MLP
    last_fused<<<NN / 32, 256, 0, stream>>>(HC, PL, srcS, rowptr, eaS,
                                            WeL, beL, WnL, bnL, out);
}

// Round 14
// 427.764 us; speedup vs baseline: 1.5540x; 1.0438x over previous
//
#include <hip/hip_runtime.h>

#define NN 20000
#define NE 320000
#define HD 128
#define NBLK ((NN + 255) / 256)   // 79

typedef short     s16x8 __attribute__((ext_vector_type(8)));
typedef unsigned short u16x8 __attribute__((ext_vector_type(8)));
typedef float     f32x4 __attribute__((ext_vector_type(4)));

__device__ __forceinline__ float b2f(unsigned short u) {
    union { unsigned int i; float f; } c; c.i = ((unsigned int)u) << 16; return c.f;
}
__device__ __forceinline__ unsigned short f2b(float f) {
    union { float f; unsigned int i; } c; c.f = f;
    unsigned int x = c.i + 0x7FFFu + ((c.i >> 16) & 1u);
    return (unsigned short)(x >> 16);
}

// ---------------- CSR build ----------------
__global__ void zero_cnt(int* __restrict__ cnt) {
    int i = blockIdx.x * 256 + threadIdx.x;
    if (i < NN) cnt[i] = 0;
}

__global__ void hist_kernel(const int* __restrict__ ei, int* __restrict__ cnt) {
    int e = blockIdx.x * 256 + threadIdx.x;
    if (e < NE) atomicAdd(&cnt[ei[NE + e]], 1);
}

__global__ void scan1_kernel(const int* __restrict__ cnt, int* __restrict__ rowptr,
                             int* __restrict__ bsum, int* __restrict__ cursor) {
    __shared__ int s[256];
    int t = threadIdx.x;
    int i = blockIdx.x * 256 + t;
    if (i < NN) cursor[i] = 0;
    int v = (i < NN) ? cnt[i] : 0;
    s[t] = v; __syncthreads();
    #pragma unroll
    for (int off = 1; off < 256; off <<= 1) {
        int add = (t >= off) ? s[t - off] : 0;
        __syncthreads();
        s[t] += add;
        __syncthreads();
    }
    if (i < NN) rowptr[i] = s[t] - v;
    if (t == 255) bsum[blockIdx.x] = s[t];
}

__global__ void scan2_kernel(int* __restrict__ bsum, int* __restrict__ boffs) {
    __shared__ int s[256];
    int t = threadIdx.x;
    int v = (t < NBLK) ? bsum[t] : 0;
    s[t] = v; __syncthreads();
    #pragma unroll
    for (int off = 1; off < 256; off <<= 1) {
        int add = (t >= off) ? s[t - off] : 0;
        __syncthreads();
        s[t] += add;
        __syncthreads();
    }
    if (t < NBLK) boffs[t] = s[t] - v;
}

__global__ void scan3_kernel(int* __restrict__ rowptr, const int* __restrict__ boffs) {
    int i = blockIdx.x * 256 + threadIdx.x;
    if (i < NN) rowptr[i] += boffs[blockIdx.x];
    if (i == 0) rowptr[NN] = NE;
}

__global__ void scatter_kernel(const int* __restrict__ ei, const float* __restrict__ ea,
                               const int* __restrict__ rowptr, int* __restrict__ cursor,
                               int* __restrict__ srcS, float* __restrict__ eaS) {
    int e = blockIdx.x * 256 + threadIdx.x;
    if (e >= NE) return;
    int d = ei[NE + e];
    int pos = rowptr[d] + atomicAdd(&cursor[d], 1);
    srcS[pos] = ei[e];
    *(float4*)(eaS + (long long)pos * 4) = *(const float4*)(ea + (long long)e * 4);
}

// ---------------- all weight transposes in one dispatch (grid.y = 15)
__global__ void cvt_all(const float* __restrict__ WeM, const float* __restrict__ WnM,
                        const float* __restrict__ WeC, const float* __restrict__ WnC,
                        const float* __restrict__ Wn1,
                        unsigned short* __restrict__ WTeM, unsigned short* __restrict__ WTnM,
                        unsigned short* __restrict__ WTeC, unsigned short* __restrict__ WTnC,
                        unsigned short* __restrict__ WTn1) {
    int y = blockIdx.y;
    const float* W; unsigned short* WT; int K;
    if (y < 6)       { W = WeM + (size_t)y * 132 * HD;       WT = WTeM + (size_t)y * HD * 128; K = 128; }
    else if (y < 12) { int i = y - 6;
                       W = WnM + (size_t)i * 256 * HD;       WT = WTnM + (size_t)i * HD * 256; K = 256; }
    else if (y == 12){ W = WeC;                              WT = WTeC;                        K = 896; }
    else if (y == 13){ W = WnC;                              WT = WTnC;                        K = 1024; }
    else             { W = Wn1 + 8 * HD;                     WT = WTn1;                        K = 128; }
    int tid = blockIdx.x * 256 + threadIdx.x;
    if (tid >= K * HD) return;
    int n = tid & (HD - 1), k = tid >> 7;
    WT[(size_t)n * K + k] = f2b(W[(size_t)k * HD + n]);
}

// ---------------- layer-1 dual projection
__global__ void proj8_dual(const float* __restrict__ x,
                           const float* __restrict__ We1, const float* __restrict__ Wn1,
                           const float* __restrict__ bn1,
                           unsigned short* __restrict__ P, float* __restrict__ B1) {
    int t = blockIdx.x * 256 + threadIdx.x;
    int n = t >> 7, j = t & 127;
    const float* xr = x + (long long)n * 8;
    float a = 0.f, b = bn1[j];
    #pragma unroll
    for (int k = 0; k < 8; ++k) {
        float xv = xr[k];
        a = fmaf(xv, We1[k * HD + j], a);
        b = fmaf(xv, Wn1[k * HD + j], b);
    }
    P[t]  = f2b(a);
    B1[t] = b;
}

// ---------------- fused edge pass, 4-way unrolled gather pipeline
__global__ __launch_bounds__(256)
void edge_agg(const unsigned short* __restrict__ P,
              const int* __restrict__ srcS, const int* __restrict__ rowptr,
              const float* __restrict__ eaS,
              const float* __restrict__ Wea,
              const float* __restrict__ bias,
              unsigned short* __restrict__ AggB)
{
    int t  = threadIdx.x;
    int n  = blockIdx.x * 16 + (t >> 4);
    int cg = t & 15;
    float wea[4][8], bv[8];
    #pragma unroll
    for (int c = 0; c < 4; ++c)
        #pragma unroll
        for (int j = 0; j < 8; ++j) wea[c][j] = Wea[c * HD + cg * 8 + j];
    #pragma unroll
    for (int j = 0; j < 8; ++j) bv[j] = bias[cg * 8 + j];

    int s = rowptr[n], e = rowptr[n + 1];
    float acc[8];
    #pragma unroll
    for (int j = 0; j < 8; ++j) acc[j] = 0.f;

    int p = s;
    for (; p + 4 <= e; p += 4) {
        int s0 = srcS[p + 0], s1 = srcS[p + 1], s2 = srcS[p + 2], s3 = srcS[p + 3];
        u16x8 pv0 = *(const u16x8*)(P + (long long)s0 * HD + cg * 8);
        u16x8 pv1 = *(const u16x8*)(P + (long long)s1 * HD + cg * 8);
        u16x8 pv2 = *(const u16x8*)(P + (long long)s2 * HD + cg * 8);
        u16x8 pv3 = *(const u16x8*)(P + (long long)s3 * HD + cg * 8);
        float4 e0 = *(const float4*)(eaS + (long long)(p + 0) * 4);
        float4 e1 = *(const float4*)(eaS + (long long)(p + 1) * 4);
        float4 e2 = *(const float4*)(eaS + (long long)(p + 2) * 4);
        float4 e3 = *(const float4*)(eaS + (long long)(p + 3) * 4);
        #pragma unroll
        for (int j = 0; j < 8; ++j) {
            float m0 = b2f(pv0[j]) + bv[j];
            m0 = fmaf(e0.x, wea[0][j], m0); m0 = fmaf(e0.y, wea[1][j], m0);
            m0 = fmaf(e0.z, wea[2][j], m0); m0 = fmaf(e0.w, wea[3][j], m0);
            float m1 = b2f(pv1[j]) + bv[j];
            m1 = fmaf(e1.x, wea[0][j], m1); m1 = fmaf(e1.y, wea[1][j], m1);
            m1 = fmaf(e1.z, wea[2][j], m1); m1 = fmaf(e1.w, wea[3][j], m1);
            float m2 = b2f(pv2[j]) + bv[j];
            m2 = fmaf(e2.x, wea[0][j], m2); m2 = fmaf(e2.y, wea[1][j], m2);
            m2 = fmaf(e2.z, wea[2][j], m2); m2 = fmaf(e2.w, wea[3][j], m2);
            float m3 = b2f(pv3[j]) + bv[j];
            m3 = fmaf(e3.x, wea[0][j], m3); m3 = fmaf(e3.y, wea[1][j], m3);
            m3 = fmaf(e3.z, wea[2][j], m3); m3 = fmaf(e3.w, wea[3][j], m3);
            acc[j] += (fmaxf(m0, 0.f) + fmaxf(m1, 0.f)) + (fmaxf(m2, 0.f) + fmaxf(m3, 0.f));
        }
    }
    for (; p < e; ++p) {
        int src = srcS[p];
        u16x8 pv = *(const u16x8*)(P + (long long)src * HD + cg * 8);
        float4 e4 = *(const float4*)(eaS + (long long)p * 4);
        #pragma unroll
        for (int j = 0; j < 8; ++j) {
            float m = b2f(pv[j]) + bv[j];
            m = fmaf(e4.x, wea[0][j], m);
            m = fmaf(e4.y, wea[1][j], m);
            m = fmaf(e4.z, wea[2][j], m);
            m = fmaf(e4.w, wea[3][j], m);
            acc[j] += fmaxf(m, 0.f);
        }
    }
    u16x8 o;
    #pragma unroll
    for (int j = 0; j < 8; ++j) o[j] = f2b(acc[j]);
    *(u16x8*)(AggB + (long long)n * HD + cg * 8) = o;
}

// ---------------- MFMA layer kernel, BM=128, 4 waves (2x2), N=128.
// Stage 1: C = [relu](A @ WTn [+ bias | + addF]); C -> OutB and (PROJ|PROJ8) LDS Cs.
// Stage 2 PROJ : P = C @ WTe (full 128 cols, MFMA) -> Pout bf16.
// Stage 2 PROJ8: PL = C @ WeLf[:128] (8 cols, VALU) -> PLout fp32.
template<bool ACT, bool ADDF, bool PROJ, bool PROJ8>
__global__ __launch_bounds__(256)
void mfma_np(const unsigned short* __restrict__ seg1, long long s1, int xoff, int D1,
             const unsigned short* __restrict__ seg2, long long s2,
             const unsigned short* __restrict__ WTn, const float* __restrict__ bias,
             const float* __restrict__ addF,
             unsigned short* __restrict__ OutB, long long ostride, int ooff,
             const unsigned short* __restrict__ WTe,
             unsigned short* __restrict__ Pout,
             const float* __restrict__ WeLf, float* __restrict__ PLout,
             int M, int K)
{
    __shared__ unsigned short As[4 * 128 * 8];
    __shared__ unsigned short Bs[4 * 128 * 8];
    __shared__ unsigned short Cs[(PROJ || PROJ8) ? 16 * 128 * 8 : 8];
    __shared__ float sWL[PROJ8 ? 128 * 8 : 1];

    const int t    = threadIdx.x;
    const int lane = t & 63;
    const int wid  = t >> 6;
    const int wm   = wid >> 1, wn = wid & 1;
    const int ln   = lane & 15, kb = lane >> 4;
    const int bRow = blockIdx.x * 128;

    if (PROJ8) {
        for (int i = t; i < 128 * 8; i += 256) sWL[i] = WeLf[i];
    }

    const int srow = t >> 1, half = t & 1;
    int gr  = bRow + srow;
    int grc = gr < M ? gr : M - 1;
    const unsigned short* p1 = seg1 + (long long)grc * s1 + xoff;
    const unsigned short* p2 = seg2 ? seg2 + (long long)grc * s2 : nullptr;
    const unsigned short* pb = WTn + (long long)srow * K;
    const int c0 = half * 2, c1 = half * 2 + 1;

    f32x4 acc[4][4];
    #pragma unroll
    for (int m = 0; m < 4; ++m)
        #pragma unroll
        for (int n = 0; n < 4; ++n) acc[m][n] = f32x4{0.f, 0.f, 0.f, 0.f};

    const int nkt = K >> 5;
    for (int kt = 0; kt < nkt; ++kt) {
        int k0 = (kt << 5) + half * 16;
        const u16x8* sp = (k0 + 16 <= D1) ? (const u16x8*)(p1 + k0)
                                          : (const u16x8*)(p2 + (k0 - D1));
        u16x8 a0 = sp[0], a1 = sp[1];
        *(u16x8*)&As[(c0 * 128 + srow) * 8] = a0;
        *(u16x8*)&As[(c1 * 128 + srow) * 8] = a1;
        const u16x8* bp = (const u16x8*)(pb + (kt << 5) + half * 16);
        u16x8 b0 = bp[0], b1 = bp[1];
        *(u16x8*)&Bs[(c0 * 128 + srow) * 8] = b0;
        *(u16x8*)&Bs[(c1 * 128 + srow) * 8] = b1;
        __syncthreads();

        s16x8 af[4], bfr[4];
        #pragma unroll
        for (int m = 0; m < 4; ++m)
            af[m] = *(const s16x8*)&As[(kb * 128 + wm * 64 + m * 16 + ln) * 8];
        #pragma unroll
        for (int n = 0; n < 4; ++n)
            bfr[n] = *(const s16x8*)&Bs[(kb * 128 + wn * 64 + n * 16 + ln) * 8];
        #pragma unroll
        for (int m = 0; m < 4; ++m)
            #pragma unroll
            for (int n = 0; n < 4; ++n)
                acc[m][n] = __builtin_amdgcn_mfma_f32_16x16x32_bf16(af[m], bfr[n], acc[m][n], 0, 0, 0);
        __syncthreads();
    }

    // ---- epilogue 1
    float bv[4];
    if (ACT && !ADDF) {
        #pragma unroll
        for (int n = 0; n < 4; ++n) bv[n] = bias[wn * 64 + n * 16 + ln];
    }
    #pragma unroll
    for (int m = 0; m < 4; ++m) {
        #pragma unroll
        for (int r = 0; r < 4; ++r) {
            int lrow = wm * 64 + m * 16 + kb * 4 + r;
            int grow = bRow + lrow;
            int gcl  = grow < M ? grow : M - 1;
            unsigned short* op = OutB + (long long)gcl * ostride + ooff;
            const float* ap = ADDF ? addF + (long long)gcl * HD : nullptr;
            #pragma unroll
            for (int n = 0; n < 4; ++n) {
                int col = wn * 64 + n * 16 + ln;
                float v = acc[m][n][r];
                if (ADDF) v += ap[col];
                else if (ACT) v += bv[n];
                if (ACT) v = fmaxf(v, 0.f);
                unsigned short b = f2b(v);
                if (grow < M) op[col] = b;
                if (PROJ || PROJ8) {
                    int cidx = (((wn * 2 + (n >> 1)) * 4 + ((n & 1) << 1) + (ln >> 3)) * 128 + lrow) * 8 + (ln & 7);
                    Cs[cidx] = b;
                }
            }
        }
    }

    // ---- stage 2 (full 128-col projection via MFMA)
    if (PROJ) {
        f32x4 acc2[4][4];
        #pragma unroll
        for (int m = 0; m < 4; ++m)
            #pragma unroll
            for (int n = 0; n < 4; ++n) acc2[m][n] = f32x4{0.f, 0.f, 0.f, 0.f};

        const unsigned short* pb2 = WTe + (long long)srow * 128;
        for (int kt = 0; kt < 4; ++kt) {
            const u16x8* bp = (const u16x8*)(pb2 + (kt << 5) + half * 16);
            u16x8 b0 = bp[0], b1 = bp[1];
            *(u16x8*)&Bs[(c0 * 128 + srow) * 8] = b0;
            *(u16x8*)&Bs[(c1 * 128 + srow) * 8] = b1;
            __syncthreads();

            s16x8 af[4], bfr[4];
            #pragma unroll
            for (int m = 0; m < 4; ++m)
                af[m] = *(const s16x8*)&Cs[((kt * 4 + kb) * 128 + wm * 64 + m * 16 + ln) * 8];
            #pragma unroll
            for (int n = 0; n < 4; ++n)
                bfr[n] = *(const s16x8*)&Bs[(kb * 128 + wn * 64 + n * 16 + ln) * 8];
            #pragma unroll
            for (int m = 0; m < 4; ++m)
                #pragma unroll
                for (int n = 0; n < 4; ++n)
                    acc2[m][n] = __builtin_amdgcn_mfma_f32_16x16x32_bf16(af[m], bfr[n], acc2[m][n], 0, 0, 0);
            __syncthreads();
        }

        #pragma unroll
        for (int m = 0; m < 4; ++m) {
            #pragma unroll
            for (int r = 0; r < 4; ++r) {
                int grow = bRow + wm * 64 + m * 16 + kb * 4 + r;
                if (grow < M) {
                    unsigned short* op = Pout + (long long)grow * HD;
                    #pragma unroll
                    for (int n = 0; n < 4; ++n)
                        op[wn * 64 + n * 16 + ln] = f2b(acc2[m][n][r]);
                }
            }
        }
    }

    // ---- stage 2 (8-col projection via VALU): PL = C @ WeL[:128]
    if (PROJ8) {
        __syncthreads();
        int row = t >> 1;
        int j0  = (t & 1) * 4;
        int grow = bRow + row;
        float a[4] = {0.f, 0.f, 0.f, 0.f};
        #pragma unroll 4
        for (int kc = 0; kc < 16; ++kc) {
            u16x8 cv = *(const u16x8*)&Cs[(kc * 128 + row) * 8];
            #pragma unroll
            for (int kk = 0; kk < 8; ++kk) {
                float f = b2f(cv[kk]);
                #pragma unroll
                for (int j = 0; j < 4; ++j)
                    a[j] = fmaf(f, sWL[(kc * 8 + kk) * 8 + j0 + j], a[j]);
            }
        }
        if (grow < M) {
            float4 o = {a[0], a[1], a[2], a[3]};
            *(float4*)(PLout + (long long)grow * 8 + j0) = o;
        }
    }
}

// ---------------- fused last layer (Hout=8): edge agg + node MLP
__global__ __launch_bounds__(256)
void last_fused(const unsigned short* __restrict__ HC, const float* __restrict__ PL,
                const int* __restrict__ srcS, const int* __restrict__ rowptr,
                const float* __restrict__ eaS,
                const float* __restrict__ WeL, const float* __restrict__ beL,
                const float* __restrict__ WnL, const float* __restrict__ bnL,
                float* __restrict__ out)
{
    __shared__ float sWn[136 * 8];
    __shared__ float aggL[32][8];
    int t = threadIdx.x;
    for (int i = t; i < 136 * 8; i += 256) sWn[i] = WnL[i];
    int nl = t >> 3, j = t & 7;
    int n  = blockIdx.x * 32 + nl;

    float wea[4];
    #pragma unroll
    for (int c = 0; c < 4; ++c) wea[c] = WeL[(HD + c) * 8 + j];
    float bb = beL[j];
    int s = rowptr[n], e = rowptr[n + 1];
    float acc = 0.f;
    int p = s;
    for (; p + 4 <= e; p += 4) {
        int s0 = srcS[p + 0], s1 = srcS[p + 1], s2 = srcS[p + 2], s3 = srcS[p + 3];
        float q0 = PL[(long long)s0 * 8 + j], q1 = PL[(long long)s1 * 8 + j];
        float q2 = PL[(long long)s2 * 8 + j], q3 = PL[(long long)s3 * 8 + j];
        float4 e0 = *(const float4*)(eaS + (long long)(p + 0) * 4);
        float4 e1 = *(const float4*)(eaS + (long long)(p + 1) * 4);
        float4 e2 = *(const float4*)(eaS + (long long)(p + 2) * 4);
        float4 e3 = *(const float4*)(eaS + (long long)(p + 3) * 4);
        float m0 = q0 + bb;
        m0 = fmaf(e0.x, wea[0], m0); m0 = fmaf(e0.y, wea[1], m0);
        m0 = fmaf(e0.z, wea[2], m0); m0 = fmaf(e0.w, wea[3], m0);
        float m1 = q1 + bb;
        m1 = fmaf(e1.x, wea[0], m1); m1 = fmaf(e1.y, wea[1], m1);
        m1 = fmaf(e1.z, wea[2], m1); m1 = fmaf(e1.w, wea[3], m1);
        float m2 = q2 + bb;
        m2 = fmaf(e2.x, wea[0], m2); m2 = fmaf(e2.y, wea[1], m2);
        m2 = fmaf(e2.z, wea[2], m2); m2 = fmaf(e2.w, wea[3], m2);
        float m3 = q3 + bb;
        m3 = fmaf(e3.x, wea[0], m3); m3 = fmaf(e3.y, wea[1], m3);
        m3 = fmaf(e3.z, wea[2], m3); m3 = fmaf(e3.w, wea[3], m3);
        acc += (fmaxf(m0, 0.f) + fmaxf(m1, 0.f)) + (fmaxf(m2, 0.f) + fmaxf(m3, 0.f));
    }
    for (; p < e; ++p) {
        int src = srcS[p];
        float m = PL[(long long)src * 8 + j] + bb;
        float4 e4 = *(const float4*)(eaS + (long long)p * 4);
        m = fmaf(e4.x, wea[0], m);
        m = fmaf(e4.y, wea[1], m);
        m = fmaf(e4.z, wea[2], m);
        m = fmaf(e4.w, wea[3], m);
        acc += fmaxf(m, 0.f);
    }
    aggL[nl][j] = acc;
    __syncthreads();

    float o = bnL[j];
    const unsigned short* xr = HC + (long long)n * HD;
    for (int k8 = 0; k8 < HD / 8; ++k8) {
        u16x8 v = *(const u16x8*)(xr + k8 * 8);
        #pragma unroll
        for (int c = 0; c < 8; ++c)
            o = fmaf(b2f(v[c]), sWn[(k8 * 8 + c) * 8 + j], o);
    }
    #pragma unroll
    for (int c = 0; c < 8; ++c)
        o = fmaf(aggL[nl][c], sWn[(HD + c) * 8 + j], o);
    out[(long long)n * 8 + j] = fmaxf(o, 0.f);
}

extern "C" void kernel_launch(void* const* d_in, const int* in_sizes, int n_in,
                              void* d_out, int out_size, void* d_ws, size_t ws_size,
                              hipStream_t stream) {
    const float* x    = (const float*)d_in[0];
    const int*   ei   = (const int*)d_in[1];
    const float* ea   = (const float*)d_in[2];
    const float* We1  = (const float*)d_in[3];
    const float* be1  = (const float*)d_in[4];
    const float* Wn1  = (const float*)d_in[5];
    const float* bn1  = (const float*)d_in[6];
    const float* WeM  = (const float*)d_in[7];
    const float* beM  = (const float*)d_in[8];
    const float* WnM  = (const float*)d_in[9];
    const float* bnM  = (const float*)d_in[10];
    const float* WeC  = (const float*)d_in[11];
    const float* beC  = (const float*)d_in[12];
    const float* WnC  = (const float*)d_in[13];
    const float* bnC  = (const float*)d_in[14];
    const float* WeL  = (const float*)d_in[15];
    const float* beL  = (const float*)d_in[16];
    const float* WnL  = (const float*)d_in[17];
    const float* bnL  = (const float*)d_in[18];

    char* w = (char*)d_ws;
    auto alloc = [&](size_t bytes) -> char* {
        char* p = w; w += (bytes + 255) & ~(size_t)255; return p;
    };
    int*            cnt    = (int*)           alloc((size_t)NN * 4);
    int*            cursor = (int*)           alloc((size_t)NN * 4);
    int*            rowptr = (int*)           alloc((size_t)(NN + 1) * 4);
    int*            bsum   = (int*)           alloc((size_t)256 * 4);
    int*            boffs  = (int*)           alloc((size_t)256 * 4);
    int*            srcS   = (int*)           alloc((size_t)NE * 4);
    float*          eaS    = (float*)         alloc((size_t)NE * 4 * 4);
    unsigned short* Pbuf   = (unsigned short*)alloc((size_t)NN * HD * 2);
    float*          B1     = (float*)         alloc((size_t)NN * HD * 4);
    unsigned short* XS     = (unsigned short*)alloc((size_t)NN * 7 * HD * 2);
    unsigned short* HC     = (unsigned short*)alloc((size_t)NN * HD * 2);
    unsigned short* AggB   = (unsigned short*)alloc((size_t)NN * HD * 2);
    float*          PL     = (float*)         alloc((size_t)NN * 8 * 4);
    unsigned short* WTn1   = (unsigned short*)alloc((size_t)HD * 128 * 2);
    unsigned short* WTeM   = (unsigned short*)alloc((size_t)6 * HD * 128 * 2);
    unsigned short* WTnM   = (unsigned short*)alloc((size_t)6 * HD * 256 * 2);
    unsigned short* WTeC   = (unsigned short*)alloc((size_t)HD * 896 * 2);
    unsigned short* WTnC   = (unsigned short*)alloc((size_t)HD * 1024 * 2);
    float* out = (float*)d_out;

    // --- CSR build
    zero_cnt<<<NBLK, 256, 0, stream>>>(cnt);
    hist_kernel<<<(NE + 255) / 256, 256, 0, stream>>>(ei, cnt);
    scan1_kernel<<<NBLK, 256, 0, stream>>>(cnt, rowptr, bsum, cursor);
    scan2_kernel<<<1, 256, 0, stream>>>(bsum, boffs);
    scan3_kernel<<<NBLK, 256, 0, stream>>>(rowptr, boffs);
    scatter_kernel<<<(NE + 255) / 256, 256, 0, stream>>>(ei, ea, rowptr, cursor, srcS, eaS);

    // --- weight transposes (one dispatch)
    cvt_all<<<dim3(512, 15), 256, 0, stream>>>(WeM, WnM, WeC, WnC, Wn1,
                                               WTeM, WTnM, WTeC, WTnC, WTn1);

    const int ngrid = (NN + 127) / 128;    // 157
    const int agrid = NN / 16;             // 1250

    // --- layer 1: P + B1; edge; fused node+proj(L2 edge weights)
    proj8_dual<<<NN * HD / 256, 256, 0, stream>>>(x, We1, Wn1, bn1, Pbuf, B1);
    edge_agg<<<agrid, 256, 0, stream>>>(Pbuf, srcS, rowptr, eaS, We1 + 8 * HD, be1, AggB);
    mfma_np<true, true, true, false><<<ngrid, 256, 0, stream>>>(
        AggB, HD, 0, HD, nullptr, 0, WTn1, nullptr, B1,
        XS, 7 * HD, 0, WTeM, Pbuf, nullptr, nullptr, NN, 128);

    // --- layers 2..6: edge; fused node+proj(next edge weights)
    for (int i = 0; i < 5; ++i) {
        edge_agg<<<agrid, 256, 0, stream>>>(Pbuf, srcS, rowptr, eaS,
                                            WeM + (size_t)i * 132 * HD + (size_t)128 * HD,
                                            beM + i * HD, AggB);
        mfma_np<true, false, true, false><<<ngrid, 256, 0, stream>>>(
            XS, 7 * HD, i * HD, HD, AggB, HD,
            WTnM + (size_t)i * HD * 256, bnM + i * HD, nullptr,
            XS, 7 * HD, (i + 1) * HD, WTeM + (size_t)(i + 1) * HD * 128, Pbuf,
            nullptr, nullptr, NN, 256);
    }

    // --- layer 7: edge; node only
    edge_agg<<<agrid, 256, 0, stream>>>(Pbuf, srcS, rowptr, eaS,
                                        WeM + (size_t)5 * 132 * HD + (size_t)128 * HD,
                                        beM + 5 * HD, AggB);
    mfma_np<true, false, false, false><<<ngrid, 256, 0, stream>>>(
        XS, 7 * HD, 5 * HD, HD, AggB, HD,
        WTnM + (size_t)5 * HD * 256, bnM + 5 * HD, nullptr,
        XS, 7 * HD, 6 * HD, nullptr, nullptr, nullptr, nullptr, NN, 256);

    // --- concat layer: proj (K=896); edge; node (K=1024) fused with PL projection
    mfma_np<false, false, false, false><<<ngrid, 256, 0, stream>>>(
        XS, 7 * HD, 0, 7 * HD, nullptr, 0, WTeC, nullptr, nullptr,
        Pbuf, HD, 0, nullptr, nullptr, nullptr, nullptr, NN, 896);
    edge_agg<<<agrid, 256, 0, stream>>>(Pbuf, srcS, rowptr, eaS,
                                        WeC + (size_t)896 * HD, beC, AggB);
    mfma_np<true, false, false, true><<<ngrid, 256, 0, stream>>>(
        XS, 7 * HD, 0, 7 * HD, AggB, HD, WTnC, bnC, nullptr,
        HC, HD, 0, nullptr, nullptr, WeL, PL, NN, 1024);

    // --- last layer (Hout=8): fused agg + node MLP
    last_fused<<<NN / 32, 256, 0, stream>>>(HC, PL, srcS, rowptr, eaS,
                                            WeL, beL, WnL, bnL, out);
}